// Round 11
// baseline (304.769 us; speedup 1.0000x reference)
//
#include <hip/hip_runtime.h>
#include <hip/hip_cooperative_groups.h>

namespace cg = cooperative_groups;

#define N_NODES 100000
#define N_EDGES 1600000
#define NB 782     // ceil(N_NODES/128) buckets of 128 dst-nodes
#define CAP 3072   // strip capacity per bucket
#define EPBC 4096  // coop: edges per sort block (16KB stage + 8KB bid)
#define NP1C 391   // ceil(N_EDGES/EPBC)
#define EPBF 8192  // fallback: edges per sort block
#define NP1F 196   // ceil(N_EDGES/EPBF)
#define CVB 200    // fallback convert blocks
#define GRID 512   // coop grid: 2 blocks/CU x 256 CU (needs LDS<=32KB/block)
#define YP 72      // padded weight row (bf16) — unchanged (wbuf image layout)
#define AP 66      // coop agg row padding (odd int stride 33 -> conflict-free)
#define APF 72     // fallback agg row padding (measured layout)
#define WINTS 3456 // weight image ints

typedef __attribute__((ext_vector_type(8))) short bhalf8;
typedef __attribute__((ext_vector_type(4))) float f32x4;
typedef __attribute__((ext_vector_type(2))) float f32x2;

__device__ __forceinline__ unsigned short bf16r(float f) {
    unsigned u = __float_as_uint(f);
    unsigned r = (u >> 16) & 1;
    return (unsigned short)((u + 0x7fffu + r) >> 16);
}
__device__ __forceinline__ unsigned pk2(float a, float b) {
    return (unsigned)bf16r(a) | ((unsigned)bf16r(b) << 16);
}
__device__ __forceinline__ f32x2 ex2(unsigned u) {
    f32x2 r; r.x = __uint_as_float(u << 16); r.y = __uint_as_float(u & 0xffff0000u);
    return r;
}

// ===========================================================================
// fused cooperative kernel, LDS <= 32 KB/block so 2 blocks/CU co-reside even
// under a 64 KB-per-CU occupancy assumption. GRID=512.
// ===========================================================================
__global__ __launch_bounds__(512, 4) void fused(
    const float4* __restrict__ X4, uint2* __restrict__ Xb,
    const int* __restrict__ src, const int* __restrict__ dst,
    int* __restrict__ gcur, unsigned* __restrict__ ebuf,
    const float* __restrict__ W1, const float* __restrict__ W2,
    int* __restrict__ wbuf, const float* __restrict__ b1,
    int* __restrict__ goff, unsigned short* __restrict__ Zb,
    const float* __restrict__ b2, float4* __restrict__ out4) {
    // max(phase0 30864, phase1 31748, phase2 13312) = 31748
    __shared__ __align__(16) char lds[31760];
    int t = threadIdx.x, lane = t & 63, wid = t >> 6;
    int bid = blockIdx.x;
    const uint4* Xb4 = (const uint4*)Xb;
    const uint4* Zb4 = (const uint4*)Zb;

    // ---------------- phase 0: sort (bid<NP1C) || convert (rest) -------------
    if (bid < NP1C) {
        int* h   = (int*)lds;                              // [NB]   3128
        int* cur = h + NB;                                 // [NB]   3128 (lo folded in)
        int* wsum = cur + NB;                              // [8]
        unsigned* stage = (unsigned*)(lds + 6288);         // [EPBC] 16384
        unsigned short* bidv = (unsigned short*)(lds + 22672);  // [EPBC] 8192
        int e0 = bid * EPBC;
        int eN = N_EDGES - e0; if (eN > EPBC) eN = EPBC;
        for (int b = t; b < NB; b += 512) h[b] = 0;
        __syncthreads();
        for (int i = t; i < eN; i += 512) atomicAdd(&h[dst[e0 + i] >> 7], 1);
        __syncthreads();
        int i0 = 2 * t, i1 = i0 + 1;
        int v0 = (i0 < NB) ? h[i0] : 0;
        int v1 = (i1 < NB) ? h[i1] : 0;
        int ps = v0 + v1, s = ps;
        for (int o = 1; o < 64; o <<= 1) {
            int u = __shfl_up(s, o);
            if (lane >= o) s += u;
        }
        if (lane == 63) wsum[wid] = s;
        __syncthreads();
        int wofs = 0;
        for (int w = 0; w < wid; w++) wofs += wsum[w];
        int excl = wofs + s - ps;
        if (i0 < NB) cur[i0] = excl;
        if (i1 < NB) cur[i1] = excl + v0;
        __syncthreads();
        for (int b = t; b < NB; b += 512) {
            int hb = h[b];
            int ofs = hb ? atomicAdd(&gcur[b], hb) : 0;
            h[b] = b * CAP + ofs - cur[b];   // cur[b] == lo[b] here (pre-rank)
        }
        __syncthreads();
        for (int i = t; i < eN; i += 512) {
            int sd = src[e0 + i], dd = dst[e0 + i];
            int b = dd >> 7;
            int r = atomicAdd(&cur[b], 1);
            stage[r] = ((unsigned)sd << 7) | (unsigned)(dd & 127);
            bidv[r] = (unsigned short)b;
        }
        __syncthreads();
        for (int i = t; i < eN; i += 512)
            ebuf[h[bidv[i]] + i] = stage[i];
    } else {
        if (bid == NP1C) {
            unsigned short* wp = (unsigned short*)wbuf;
            for (int i = t; i < 64 * 64; i += 512) {
                int k = i >> 6, hc = i & 63;
                wp[hc * YP + k] = bf16r(W1[k * 64 + hc]);
            }
            for (int i = t; i < 64 * 32; i += 512) {
                int k = i >> 5, oc = i & 31;
                wp[2 * 2304 + oc * YP + k] = bf16r(W2[k * 32 + oc]);
            }
        }
        for (int i = (bid - NP1C) * 512 + t; i < N_NODES * 16; i += (GRID - NP1C) * 512) {
            float4 v = X4[i];
            uint2 o; o.x = pk2(v.x, v.y); o.y = pk2(v.z, v.w);
            Xb[i] = o;
        }
    }
    cg::this_grid().sync();

    // ---------------- phase 1: bucket1 over buckets bid, bid+GRID ------------
    {
        unsigned short* agg = (unsigned short*)lds;        // 128*AP*2 = 16896
        int* pool = (int*)(lds + 16896);                   // 13824
        int* hh = (int*)(lds + 30720);                     // [128]
        int* nodeoff = (int*)(lds + 31232);                // [129]
        int* scv = (int*)lds;                              // aliases agg (pre-gather only)
        int* stg = pool;
        unsigned short* sW1t = (unsigned short*)pool;
        unsigned short* sW2t = (unsigned short*)(pool + 2304);

        for (int bb = bid; bb < NB; bb += GRID) {
            int base = bb * CAP, cnt = gcur[bb];
            if (t < 128) hh[t] = 0;
            __syncthreads();
            unsigned ev[6]; int ek = 0;
            for (int i = t; i < cnt; i += 512) {
                unsigned v = ebuf[base + i];
                ev[ek++] = v;
                atomicAdd(&hh[v & 127], 1);
            }
            __syncthreads();
            if (wid == 0) {
                int v0 = hh[2 * lane], v1 = hh[2 * lane + 1];
                int ps = v0 + v1, s = ps;
                for (int o = 1; o < 64; o <<= 1) {
                    int u = __shfl_up(s, o);
                    if (lane >= o) s += u;
                }
                int excl = s - ps;
                nodeoff[2 * lane] = excl;
                nodeoff[2 * lane + 1] = excl + v0;
            }
            __syncthreads();
            if (t < 128) scv[t] = nodeoff[t];
            __syncthreads();
            for (int k = 0; k < ek; k++) {
                unsigned v = ev[k];
                int r = atomicAdd(&scv[v & 127], 1);
                stg[r] = (int)(v >> 7);
            }
            __syncthreads();

            for (int i = t; i < cnt; i += 512) ebuf[base + i] = (unsigned)stg[i];
            if (t < 128) goff[bb * 128 + t] = nodeoff[t];

            int il = lane & 7, g = lane >> 3;
#pragma unroll
            for (int half = 0; half < 2; half++) {
                int nl = wid * 16 + half * 8 + g;
                int s0 = nodeoff[nl], d = hh[nl];
                f32x2 p0 = {0.f, 0.f}, p1 = {0.f, 0.f}, p2 = {0.f, 0.f}, p3 = {0.f, 0.f};
                int j = 0;
                for (; j + 7 < d; j += 8) {
                    int s_[8];
#pragma unroll
                    for (int q = 0; q < 8; q++) s_[q] = stg[s0 + j + q];
                    uint4 v_[8];
#pragma unroll
                    for (int q = 0; q < 8; q++) v_[q] = Xb4[s_[q] * 8 + il];
#pragma unroll
                    for (int q = 0; q < 8; q++) {
                        p0 += ex2(v_[q].x); p1 += ex2(v_[q].y);
                        p2 += ex2(v_[q].z); p3 += ex2(v_[q].w);
                    }
                }
                for (; j + 3 < d; j += 4) {
                    int s_[4];
#pragma unroll
                    for (int q = 0; q < 4; q++) s_[q] = stg[s0 + j + q];
                    uint4 v_[4];
#pragma unroll
                    for (int q = 0; q < 4; q++) v_[q] = Xb4[s_[q] * 8 + il];
#pragma unroll
                    for (int q = 0; q < 4; q++) {
                        p0 += ex2(v_[q].x); p1 += ex2(v_[q].y);
                        p2 += ex2(v_[q].z); p3 += ex2(v_[q].w);
                    }
                }
                for (; j < d; j++) {
                    int sa = stg[s0 + j];
                    uint4 va = Xb4[sa * 8 + il];
                    p0 += ex2(va.x); p1 += ex2(va.y);
                    p2 += ex2(va.z); p3 += ex2(va.w);
                }
                uint4 o;
                o.x = pk2(p0.x, p0.y); o.y = pk2(p1.x, p1.y);
                o.z = pk2(p2.x, p2.y); o.w = pk2(p3.x, p3.y);
                *(uint4*)&agg[nl * AP + il * 8] = o;
            }
            __syncthreads();

            for (int i = t; i < WINTS; i += 512) pool[i] = wbuf[i];
            __syncthreads();

            {
                int m = lane & 15, quad = lane >> 4;
                int nl = wid * 16 + m;
                int node = bb * 128 + nl;
                bhalf8 Bc0 = *(const bhalf8*)&agg[nl * AP + quad * 8];
                bhalf8 Bc1 = *(const bhalf8*)&agg[nl * AP + 32 + quad * 8];
                unsigned short* ys = &agg[nl * AP];
#pragma unroll
                for (int tile = 0; tile < 4; tile++) {
                    f32x4 a;
#pragma unroll
                    for (int r = 0; r < 4; r++) a[r] = b1[tile * 16 + quad * 4 + r];
                    bhalf8 A0 = *(const bhalf8*)&sW1t[(tile * 16 + m) * YP + quad * 8];
                    bhalf8 A1 = *(const bhalf8*)&sW1t[(tile * 16 + m) * YP + 32 + quad * 8];
                    a = __builtin_amdgcn_mfma_f32_16x16x32_bf16(A0, Bc0, a, 0, 0, 0);
                    a = __builtin_amdgcn_mfma_f32_16x16x32_bf16(A1, Bc1, a, 0, 0, 0);
                    float y0 = a[0] > 0.f ? a[0] : 0.f, y1 = a[1] > 0.f ? a[1] : 0.f;
                    float y2 = a[2] > 0.f ? a[2] : 0.f, y3 = a[3] > 0.f ? a[3] : 0.f;
                    uint2 o; o.x = pk2(y0, y1); o.y = pk2(y2, y3);
                    *(uint2*)&ys[tile * 16 + quad * 4] = o;
                }
                __asm__ __volatile__("s_waitcnt lgkmcnt(0)" ::: "memory");
                union { bhalf8 v; uint2 u2[2]; } Y0, Y1;
                Y0.u2[0] = *(uint2*)&ys[quad * 8];
                Y0.u2[1] = *(uint2*)&ys[quad * 8 + 4];
                Y1.u2[0] = *(uint2*)&ys[32 + quad * 8];
                Y1.u2[1] = *(uint2*)&ys[32 + quad * 8 + 4];
#pragma unroll
                for (int tile = 0; tile < 2; tile++) {
                    bhalf8 A0 = *(const bhalf8*)&sW2t[(tile * 16 + m) * YP + quad * 8];
                    bhalf8 A1 = *(const bhalf8*)&sW2t[(tile * 16 + m) * YP + 32 + quad * 8];
                    f32x4 z = {0.f, 0.f, 0.f, 0.f};
                    z = __builtin_amdgcn_mfma_f32_16x16x32_bf16(A0, Y0.v, z, 0, 0, 0);
                    z = __builtin_amdgcn_mfma_f32_16x16x32_bf16(A1, Y1.v, z, 0, 0, 0);
                    if (node < N_NODES) {
                        uint2 o; o.x = pk2(z[0], z[1]); o.y = pk2(z[2], z[3]);
                        *(uint2*)&Zb[(size_t)node * 32 + tile * 16 + quad * 4] = o;
                    }
                }
            }
            __syncthreads();
        }
    }
    cg::this_grid().sync();

    // ---------------- phase 2: bucket2 over buckets bid, bid+GRID ------------
    {
        int* noff = (int*)lds;
        int* stg2 = (int*)(lds + 1024);
        for (int bb = bid; bb < NB; bb += GRID) {
            int base = bb * CAP, cnt = gcur[bb];
            if (t < 128) noff[t] = goff[bb * 128 + t];
            if (t == 128) noff[128] = cnt;
            for (int i = t; i < cnt; i += 512) stg2[i] = (int)ebuf[base + i];
            __syncthreads();

            int il = lane & 3, g = lane >> 2;
            int nl = wid * 16 + g;
            int s0 = noff[nl], d = noff[nl + 1] - s0;
            f32x2 p0 = {0.f, 0.f}, p1 = {0.f, 0.f}, p2 = {0.f, 0.f}, p3 = {0.f, 0.f};
            int j = 0;
            for (; j + 7 < d; j += 8) {
                int s_[8];
#pragma unroll
                for (int q = 0; q < 8; q++) s_[q] = stg2[s0 + j + q];
                uint4 v_[8];
#pragma unroll
                for (int q = 0; q < 8; q++) v_[q] = Zb4[s_[q] * 4 + il];
#pragma unroll
                for (int q = 0; q < 8; q++) {
                    p0 += ex2(v_[q].x); p1 += ex2(v_[q].y);
                    p2 += ex2(v_[q].z); p3 += ex2(v_[q].w);
                }
            }
            for (; j + 3 < d; j += 4) {
                int s_[4];
#pragma unroll
                for (int q = 0; q < 4; q++) s_[q] = stg2[s0 + j + q];
                uint4 v_[4];
#pragma unroll
                for (int q = 0; q < 4; q++) v_[q] = Zb4[s_[q] * 4 + il];
#pragma unroll
                for (int q = 0; q < 4; q++) {
                    p0 += ex2(v_[q].x); p1 += ex2(v_[q].y);
                    p2 += ex2(v_[q].z); p3 += ex2(v_[q].w);
                }
            }
            for (; j < d; j++) {
                int sa = stg2[s0 + j];
                uint4 va = Zb4[sa * 4 + il];
                p0 += ex2(va.x); p1 += ex2(va.y);
                p2 += ex2(va.z); p3 += ex2(va.w);
            }
            int node = bb * 128 + nl;
            if (node < N_NODES) {
                float4 bbA = ((const float4*)b2)[il * 2];
                float4 bbB = ((const float4*)b2)[il * 2 + 1];
                float4 oA, oB;
                oA.x = p0.x + bbA.x; oA.y = p0.y + bbA.y; oA.z = p1.x + bbA.z; oA.w = p1.y + bbA.w;
                oB.x = p2.x + bbB.x; oB.y = p2.y + bbB.y; oB.z = p3.x + bbB.z; oB.w = p3.y + bbB.w;
                out4[node * 8 + il * 2] = oA;
                out4[node * 8 + il * 2 + 1] = oB;
            }
            __syncthreads();
        }
    }
}

// ===========================================================================
// fallback: the measured R6 three-kernel pipeline (verbatim, 159.1 us)
// ===========================================================================
__global__ __launch_bounds__(512) void prep(const float4* __restrict__ X4,
                                            uint2* __restrict__ Xb,
                                            const int* __restrict__ src,
                                            const int* __restrict__ dst,
                                            int* __restrict__ gcur,
                                            unsigned* __restrict__ ebuf,
                                            const float* __restrict__ W1,
                                            const float* __restrict__ W2,
                                            int* __restrict__ wbuf) {
    __shared__ int h[NB];
    __shared__ int lo[NB];
    __shared__ int cur[NB];
    __shared__ int wsum[8];
    __shared__ unsigned stage[EPBF];
    __shared__ unsigned short bid[EPBF];
    int t = threadIdx.x, lane = t & 63, wid = t >> 6;
    if (blockIdx.x >= NP1F) {
        if (blockIdx.x == NP1F) {
            unsigned short* wp = (unsigned short*)wbuf;
            for (int i = t; i < 64 * 64; i += 512) {
                int k = i >> 6, hc = i & 63;
                wp[hc * YP + k] = bf16r(W1[k * 64 + hc]);
            }
            for (int i = t; i < 64 * 32; i += 512) {
                int k = i >> 5, oc = i & 31;
                wp[2 * 2304 + oc * YP + k] = bf16r(W2[k * 32 + oc]);
            }
        }
        for (int i = (blockIdx.x - NP1F) * 512 + t; i < N_NODES * 16; i += CVB * 512) {
            float4 v = X4[i];
            uint2 o; o.x = pk2(v.x, v.y); o.y = pk2(v.z, v.w);
            Xb[i] = o;
        }
        return;
    }
    int e0 = blockIdx.x * EPBF;
    int eN = N_EDGES - e0; if (eN > EPBF) eN = EPBF;
    for (int b = t; b < NB; b += 512) h[b] = 0;
    __syncthreads();
    for (int i = t; i < eN; i += 512) atomicAdd(&h[dst[e0 + i] >> 7], 1);
    __syncthreads();
    int i0 = 2 * t, i1 = i0 + 1;
    int v0 = (i0 < NB) ? h[i0] : 0;
    int v1 = (i1 < NB) ? h[i1] : 0;
    int ps = v0 + v1, s = ps;
    for (int o = 1; o < 64; o <<= 1) {
        int u = __shfl_up(s, o);
        if (lane >= o) s += u;
    }
    if (lane == 63) wsum[wid] = s;
    __syncthreads();
    int wofs = 0;
    for (int w = 0; w < wid; w++) wofs += wsum[w];
    int excl = wofs + s - ps;
    if (i0 < NB) lo[i0] = excl;
    if (i1 < NB) lo[i1] = excl + v0;
    __syncthreads();
    for (int b = t; b < NB; b += 512) {
        int hb = h[b];
        int ofs = hb ? atomicAdd(&gcur[b], hb) : 0;
        h[b] = b * CAP + ofs - lo[b];
        cur[b] = lo[b];
    }
    __syncthreads();
    for (int i = t; i < eN; i += 512) {
        int sd = src[e0 + i], dd = dst[e0 + i];
        int b = dd >> 7;
        int r = atomicAdd(&cur[b], 1);
        stage[r] = ((unsigned)sd << 7) | (unsigned)(dd & 127);
        bid[r] = (unsigned short)b;
    }
    __syncthreads();
    for (int i = t; i < eN; i += 512)
        ebuf[h[bid[i]] + i] = stage[i];
}

__global__ __launch_bounds__(512, 4) void bucket1(
    unsigned* __restrict__ ebuf, const int* __restrict__ gcur,
    const uint4* __restrict__ Xb4,
    const int* __restrict__ wbuf, const float* __restrict__ b1,
    int* __restrict__ goff,
    unsigned short* __restrict__ Zb) {
    __shared__ int hh[128], nodeoff[129], scv[128];
    __shared__ unsigned short agg[128 * APF];
    __shared__ int pool[WINTS];
    int* stg = pool;
    unsigned short* sW1t = (unsigned short*)pool;
    unsigned short* sW2t = (unsigned short*)(pool + 2304);

    int b = blockIdx.x, t = threadIdx.x;
    int base = b * CAP, cnt = gcur[b];
    int lane = t & 63, wid = t >> 6;
    if (t < 128) hh[t] = 0;
    __syncthreads();
    unsigned ev[6]; int ek = 0;
    for (int i = t; i < cnt; i += 512) {
        unsigned v = ebuf[base + i];
        ev[ek++] = v;
        atomicAdd(&hh[v & 127], 1);
    }
    __syncthreads();
    if (wid == 0) {
        int v0 = hh[2 * lane], v1 = hh[2 * lane + 1];
        int ps = v0 + v1, s = ps;
        for (int o = 1; o < 64; o <<= 1) {
            int u = __shfl_up(s, o);
            if (lane >= o) s += u;
        }
        int excl = s - ps;
        nodeoff[2 * lane] = excl;
        nodeoff[2 * lane + 1] = excl + v0;
    }
    __syncthreads();
    if (t < 128) scv[t] = nodeoff[t];
    __syncthreads();
    for (int k = 0; k < ek; k++) {
        unsigned v = ev[k];
        int r = atomicAdd(&scv[v & 127], 1);
        stg[r] = (int)(v >> 7);
    }
    __syncthreads();

    for (int i = t; i < cnt; i += 512) ebuf[base + i] = (unsigned)stg[i];
    if (t < 128) goff[b * 128 + t] = nodeoff[t];

    int il = lane & 7, g = lane >> 3;
#pragma unroll
    for (int half = 0; half < 2; half++) {
        int nl = wid * 16 + half * 8 + g;
        int s0 = nodeoff[nl], d = hh[nl];
        f32x2 p0 = {0.f, 0.f}, p1 = {0.f, 0.f}, p2 = {0.f, 0.f}, p3 = {0.f, 0.f};
        int j = 0;
        for (; j + 7 < d; j += 8) {
            int s_[8];
#pragma unroll
            for (int q = 0; q < 8; q++) s_[q] = stg[s0 + j + q];
            uint4 v_[8];
#pragma unroll
            for (int q = 0; q < 8; q++) v_[q] = Xb4[s_[q] * 8 + il];
#pragma unroll
            for (int q = 0; q < 8; q++) {
                p0 += ex2(v_[q].x); p1 += ex2(v_[q].y);
                p2 += ex2(v_[q].z); p3 += ex2(v_[q].w);
            }
        }
        for (; j + 3 < d; j += 4) {
            int s_[4];
#pragma unroll
            for (int q = 0; q < 4; q++) s_[q] = stg[s0 + j + q];
            uint4 v_[4];
#pragma unroll
            for (int q = 0; q < 4; q++) v_[q] = Xb4[s_[q] * 8 + il];
#pragma unroll
            for (int q = 0; q < 4; q++) {
                p0 += ex2(v_[q].x); p1 += ex2(v_[q].y);
                p2 += ex2(v_[q].z); p3 += ex2(v_[q].w);
            }
        }
        for (; j < d; j++) {
            int sa = stg[s0 + j];
            uint4 va = Xb4[sa * 8 + il];
            p0 += ex2(va.x); p1 += ex2(va.y);
            p2 += ex2(va.z); p3 += ex2(va.w);
        }
        uint4 o;
        o.x = pk2(p0.x, p0.y); o.y = pk2(p1.x, p1.y);
        o.z = pk2(p2.x, p2.y); o.w = pk2(p3.x, p3.y);
        *(uint4*)&agg[nl * APF + il * 8] = o;
    }
    __syncthreads();

    for (int i = t; i < WINTS; i += 512) pool[i] = wbuf[i];
    __syncthreads();

    {
        int m = lane & 15, quad = lane >> 4;
        int nl = wid * 16 + m;
        int node = b * 128 + nl;
        bhalf8 Bc0 = *(const bhalf8*)&agg[nl * APF + quad * 8];
        bhalf8 Bc1 = *(const bhalf8*)&agg[nl * APF + 32 + quad * 8];
        unsigned short* ys = &agg[nl * APF];
#pragma unroll
        for (int tile = 0; tile < 4; tile++) {
            f32x4 a;
#pragma unroll
            for (int r = 0; r < 4; r++) a[r] = b1[tile * 16 + quad * 4 + r];
            bhalf8 A0 = *(const bhalf8*)&sW1t[(tile * 16 + m) * YP + quad * 8];
            bhalf8 A1 = *(const bhalf8*)&sW1t[(tile * 16 + m) * YP + 32 + quad * 8];
            a = __builtin_amdgcn_mfma_f32_16x16x32_bf16(A0, Bc0, a, 0, 0, 0);
            a = __builtin_amdgcn_mfma_f32_16x16x32_bf16(A1, Bc1, a, 0, 0, 0);
            float y0 = a[0] > 0.f ? a[0] : 0.f, y1 = a[1] > 0.f ? a[1] : 0.f;
            float y2 = a[2] > 0.f ? a[2] : 0.f, y3 = a[3] > 0.f ? a[3] : 0.f;
            uint2 o; o.x = pk2(y0, y1); o.y = pk2(y2, y3);
            *(uint2*)&ys[tile * 16 + quad * 4] = o;
        }
        __asm__ __volatile__("s_waitcnt lgkmcnt(0)" ::: "memory");
        union { bhalf8 v; uint2 u2[2]; } Y0, Y1;
        Y0.u2[0] = *(uint2*)&ys[quad * 8];
        Y0.u2[1] = *(uint2*)&ys[quad * 8 + 4];
        Y1.u2[0] = *(uint2*)&ys[32 + quad * 8];
        Y1.u2[1] = *(uint2*)&ys[32 + quad * 8 + 4];
#pragma unroll
        for (int tile = 0; tile < 2; tile++) {
            bhalf8 A0 = *(const bhalf8*)&sW2t[(tile * 16 + m) * YP + quad * 8];
            bhalf8 A1 = *(const bhalf8*)&sW2t[(tile * 16 + m) * YP + 32 + quad * 8];
            f32x4 z = {0.f, 0.f, 0.f, 0.f};
            z = __builtin_amdgcn_mfma_f32_16x16x32_bf16(A0, Y0.v, z, 0, 0, 0);
            z = __builtin_amdgcn_mfma_f32_16x16x32_bf16(A1, Y1.v, z, 0, 0, 0);
            if (node < N_NODES) {
                uint2 o; o.x = pk2(z[0], z[1]); o.y = pk2(z[2], z[3]);
                *(uint2*)&Zb[(size_t)node * 32 + tile * 16 + quad * 4] = o;
            }
        }
    }
}

__global__ __launch_bounds__(512, 4) void bucket2(
    const unsigned* __restrict__ ebuf, const int* __restrict__ gcur,
    const int* __restrict__ goff,
    const uint4* __restrict__ Zb4,
    const float* __restrict__ b2, float4* __restrict__ out4) {
    __shared__ int noff[129];
    __shared__ int stg[CAP];
    int b = blockIdx.x, t = threadIdx.x;
    int base = b * CAP, cnt = gcur[b];
    int lane = t & 63, wid = t >> 6;
    if (t < 128) noff[t] = goff[b * 128 + t];
    if (t == 128) noff[128] = cnt;
    for (int i = t; i < cnt; i += 512) stg[i] = (int)ebuf[base + i];
    __syncthreads();

    int il = lane & 3, g = lane >> 2;
    int nl = wid * 16 + g;
    int s0 = noff[nl], d = noff[nl + 1] - s0;
    f32x2 p0 = {0.f, 0.f}, p1 = {0.f, 0.f}, p2 = {0.f, 0.f}, p3 = {0.f, 0.f};
    int j = 0;
    for (; j + 7 < d; j += 8) {
        int s_[8];
#pragma unroll
        for (int q = 0; q < 8; q++) s_[q] = stg[s0 + j + q];
        uint4 v_[8];
#pragma unroll
        for (int q = 0; q < 8; q++) v_[q] = Zb4[s_[q] * 4 + il];
#pragma unroll
        for (int q = 0; q < 8; q++) {
            p0 += ex2(v_[q].x); p1 += ex2(v_[q].y);
            p2 += ex2(v_[q].z); p3 += ex2(v_[q].w);
        }
    }
    for (; j + 3 < d; j += 4) {
        int s_[4];
#pragma unroll
        for (int q = 0; q < 4; q++) s_[q] = stg[s0 + j + q];
        uint4 v_[4];
#pragma unroll
        for (int q = 0; q < 4; q++) v_[q] = Zb4[s_[q] * 4 + il];
#pragma unroll
        for (int q = 0; q < 4; q++) {
            p0 += ex2(v_[q].x); p1 += ex2(v_[q].y);
            p2 += ex2(v_[q].z); p3 += ex2(v_[q].w);
        }
    }
    for (; j < d; j++) {
        int sa = stg[s0 + j];
        uint4 va = Zb4[sa * 4 + il];
        p0 += ex2(va.x); p1 += ex2(va.y);
        p2 += ex2(va.z); p3 += ex2(va.w);
    }
    int node = b * 128 + nl;
    if (node < N_NODES) {
        float4 bbA = ((const float4*)b2)[il * 2];
        float4 bbB = ((const float4*)b2)[il * 2 + 1];
        float4 oA, oB;
        oA.x = p0.x + bbA.x; oA.y = p0.y + bbA.y; oA.z = p1.x + bbA.z; oA.w = p1.y + bbA.w;
        oB.x = p2.x + bbB.x; oB.y = p2.y + bbB.y; oB.z = p3.x + bbB.z; oB.w = p3.y + bbB.w;
        out4[node * 8 + il * 2] = oA;
        out4[node * 8 + il * 2 + 1] = oB;
    }
}

extern "C" void kernel_launch(void* const* d_in, const int* in_sizes, int n_in,
                              void* d_out, int out_size, void* d_ws, size_t ws_size,
                              hipStream_t stream) {
    const float* features = (const float*)d_in[0];
    const int*   src      = (const int*)d_in[1];
    const int*   dst      = (const int*)d_in[2];
    const float* W1       = (const float*)d_in[3];
    const float* b1       = (const float*)d_in[4];
    const float* W2       = (const float*)d_in[5];
    const float* b2       = (const float*)d_in[6];

    char* p = (char*)d_ws;
    int* gcur = (int*)p;           p += 1024 * 4;
    unsigned* ebuf = (unsigned*)p; p += (size_t)NB * CAP * 4;
    uint2* Xb = (uint2*)p;         p += (size_t)N_NODES * 64 * 2;
    unsigned short* Zb = (unsigned short*)p; p += (size_t)N_NODES * 32 * 2;
    int* wbuf = (int*)p;           p += (size_t)WINTS * 4;
    int* goff = (int*)p;           p += (size_t)NB * 128 * 4;

    hipMemsetAsync(gcur, 0, NB * sizeof(int), stream);

    const float4* X4 = (const float4*)features;
    float4* out4 = (float4*)d_out;
    void* args[] = {
        (void*)&X4, (void*)&Xb, (void*)&src, (void*)&dst,
        (void*)&gcur, (void*)&ebuf, (void*)&W1, (void*)&W2,
        (void*)&wbuf, (void*)&b1, (void*)&goff, (void*)&Zb,
        (void*)&b2, (void*)&out4,
    };
    hipError_t err = hipLaunchCooperativeKernel((void*)fused, dim3(GRID), dim3(512),
                                                args, 0, stream);
    if (err != hipSuccess) {
        // fallback: measured three-kernel pipeline (R6 baseline, 159.1 us)
        prep<<<NP1F + CVB, 512, 0, stream>>>(X4, Xb, src, dst, gcur, ebuf, W1, W2, wbuf);
        bucket1<<<NB, 512, 0, stream>>>(ebuf, gcur, (const uint4*)Xb, wbuf, b1, goff, Zb);
        bucket2<<<NB, 512, 0, stream>>>(ebuf, gcur, goff, (const uint4*)Zb, b2, out4);
    }
}

// Round 13
// 158.525 us; speedup vs baseline: 1.9225x; 1.9225x over previous
//
#include <hip/hip_runtime.h>

#define N_NODES 100000
#define N_EDGES 1600000
#define NB 782    // ceil(N_NODES/128) buckets of 128 dst-nodes
#define CAP 3072  // strip capacity per bucket (mean 2046, sigma 45 -> 22-sigma safe)
#define EPB 8192  // edges per pass1 block
#define NP1 196   // ceil(N_EDGES/EPB)
#define CVB 200   // convert blocks in prep
#define YP 72     // padded LDS row (bf16) for weights
#define AP 72     // padded LDS agg row (bf16)
#define WINTS 3456  // weight image: (64*72 + 32*72) ushorts = 3456 ints

typedef __attribute__((ext_vector_type(8))) short bhalf8;
typedef __attribute__((ext_vector_type(4))) float f32x4;
typedef __attribute__((ext_vector_type(2))) float f32x2;

__device__ __forceinline__ unsigned short bf16r(float f) {
    unsigned u = __float_as_uint(f);
    unsigned r = (u >> 16) & 1;
    return (unsigned short)((u + 0x7fffu + r) >> 16);
}
__device__ __forceinline__ unsigned pk2(float a, float b) {
    return (unsigned)bf16r(a) | ((unsigned)bf16r(b) << 16);
}
// expand a packed bf16 pair into an f32x2 so the accumulate is one v_pk_add_f32
__device__ __forceinline__ f32x2 ex2(unsigned u) {
    f32x2 r; r.x = __uint_as_float(u << 16); r.y = __uint_as_float(u & 0xffff0000u);
    return r;
}

// ---------------- prep: pass1 sort (blocks 0..NP1-1) || convert (rest) ---------
__global__ __launch_bounds__(512) void prep(const float4* __restrict__ X4,
                                            uint2* __restrict__ Xb,
                                            const int* __restrict__ src,
                                            const int* __restrict__ dst,
                                            int* __restrict__ gcur,
                                            unsigned* __restrict__ ebuf,
                                            const float* __restrict__ W1,
                                            const float* __restrict__ W2,
                                            int* __restrict__ wbuf) {
    __shared__ int h[NB];                // hist, then gdelta
    __shared__ int lo[NB];
    __shared__ int cur[NB];
    __shared__ int wsum[8];
    __shared__ unsigned stage[EPB];      // 32 KB
    __shared__ unsigned short bid[EPB];  // 16 KB
    int t = threadIdx.x, lane = t & 63, wid = t >> 6;
    if (blockIdx.x >= NP1) {  // convert branch
        if (blockIdx.x == NP1) {  // one block converts weights into the image
            unsigned short* wp = (unsigned short*)wbuf;
            for (int i = t; i < 64 * 64; i += 512) {
                int k = i >> 6, hc = i & 63;
                wp[hc * YP + k] = bf16r(W1[k * 64 + hc]);
            }
            for (int i = t; i < 64 * 32; i += 512) {
                int k = i >> 5, oc = i & 31;
                wp[2 * 2304 + oc * YP + k] = bf16r(W2[k * 32 + oc]);
            }
        }
        for (int i = (blockIdx.x - NP1) * 512 + t; i < N_NODES * 16; i += CVB * 512) {
            float4 v = X4[i];
            uint2 o; o.x = pk2(v.x, v.y); o.y = pk2(v.z, v.w);
            Xb[i] = o;
        }
        return;
    }
    int e0 = blockIdx.x * EPB;
    int eN = N_EDGES - e0; if (eN > EPB) eN = EPB;
    for (int b = t; b < NB; b += 512) h[b] = 0;
    __syncthreads();
    for (int i = t; i < eN; i += 512) atomicAdd(&h[dst[e0 + i] >> 7], 1);
    __syncthreads();
    int i0 = 2 * t, i1 = i0 + 1;
    int v0 = (i0 < NB) ? h[i0] : 0;
    int v1 = (i1 < NB) ? h[i1] : 0;
    int ps = v0 + v1, s = ps;
    for (int o = 1; o < 64; o <<= 1) {
        int u = __shfl_up(s, o);
        if (lane >= o) s += u;
    }
    if (lane == 63) wsum[wid] = s;
    __syncthreads();
    int wofs = 0;
    for (int w = 0; w < wid; w++) wofs += wsum[w];
    int excl = wofs + s - ps;
    if (i0 < NB) lo[i0] = excl;
    if (i1 < NB) lo[i1] = excl + v0;
    __syncthreads();
    for (int b = t; b < NB; b += 512) {
        int hb = h[b];
        int ofs = hb ? atomicAdd(&gcur[b], hb) : 0;
        h[b] = b * CAP + ofs - lo[b];
        cur[b] = lo[b];
    }
    __syncthreads();
    for (int i = t; i < eN; i += 512) {
        int sd = src[e0 + i], dd = dst[e0 + i];
        int b = dd >> 7;
        int r = atomicAdd(&cur[b], 1);
        stage[r] = ((unsigned)sd << 7) | (unsigned)(dd & 127);
        bid[r] = (unsigned short)b;
    }
    __syncthreads();
    for (int i = t; i < eN; i += 512)
        ebuf[h[bid[i]] + i] = stage[i];
}

// ---------------- bucket1: rank-sort + group-per-node gather + MFMA gemm -------
__global__ __launch_bounds__(512, 4) void bucket1(
    unsigned* __restrict__ ebuf, const int* __restrict__ gcur,
    const uint4* __restrict__ Xb4,
    const int* __restrict__ wbuf, const float* __restrict__ b1,
    int* __restrict__ goff,
    unsigned short* __restrict__ Zb) {
    __shared__ int hh[128], nodeoff[129], scv[128];
    __shared__ unsigned short agg[128 * AP];   // 18432 B agg tile [nl][ch] (bf16)
    __shared__ int pool[WINTS];                // 13824 B: stg (12288) / weights
    int* stg = pool;
    unsigned short* sW1t = (unsigned short*)pool;           // 9216 B  W1^T [h][k]
    unsigned short* sW2t = (unsigned short*)(pool + 2304);  // 4608 B  W2^T [oc][h]

    int b = blockIdx.x, t = threadIdx.x;
    int base = b * CAP, cnt = gcur[b];
    int lane = t & 63, wid = t >> 6;
    if (t < 128) hh[t] = 0;
    __syncthreads();
    unsigned ev[6]; int ek = 0;
    for (int i = t; i < cnt; i += 512) {
        unsigned v = ebuf[base + i];
        ev[ek++] = v;
        atomicAdd(&hh[v & 127], 1);
    }
    __syncthreads();
    if (wid == 0) {  // wave-parallel exclusive scan of 128 (2 elems/lane)
        int v0 = hh[2 * lane], v1 = hh[2 * lane + 1];
        int ps = v0 + v1, s = ps;
        for (int o = 1; o < 64; o <<= 1) {
            int u = __shfl_up(s, o);
            if (lane >= o) s += u;
        }
        int excl = s - ps;
        nodeoff[2 * lane] = excl;
        nodeoff[2 * lane + 1] = excl + v0;
    }
    __syncthreads();
    if (t < 128) scv[t] = nodeoff[t];
    __syncthreads();
    for (int k = 0; k < ek; k++) {
        unsigned v = ev[k];
        int r = atomicAdd(&scv[v & 127], 1);
        stg[r] = (int)(v >> 7);
    }
    __syncthreads();

    // ---- persist sorted order + offsets for bucket2 (coalesced) --------------
    for (int i = t; i < cnt; i += 512) ebuf[base + i] = (unsigned)stg[i];
    if (t < 128) goff[b * 128 + t] = nodeoff[t];

    // ---- gather: 8-lane group owns one node (8 ch/lane), 8 rows in flight ----
    int il = lane & 7, g = lane >> 3;
#pragma unroll
    for (int half = 0; half < 2; half++) {
        int nl = wid * 16 + half * 8 + g;
        int s0 = nodeoff[nl], d = hh[nl];
        f32x2 p0 = {0.f, 0.f}, p1 = {0.f, 0.f}, p2 = {0.f, 0.f}, p3 = {0.f, 0.f};
        int j = 0;
        for (; j + 7 < d; j += 8) {  // 8 loads in flight
            int s_[8];
#pragma unroll
            for (int q = 0; q < 8; q++) s_[q] = stg[s0 + j + q];
            uint4 v_[8];
#pragma unroll
            for (int q = 0; q < 8; q++) v_[q] = Xb4[s_[q] * 8 + il];
#pragma unroll
            for (int q = 0; q < 8; q++) {
                p0 += ex2(v_[q].x); p1 += ex2(v_[q].y);
                p2 += ex2(v_[q].z); p3 += ex2(v_[q].w);
            }
        }
        for (; j + 3 < d; j += 4) {
            int s_[4];
#pragma unroll
            for (int q = 0; q < 4; q++) s_[q] = stg[s0 + j + q];
            uint4 v_[4];
#pragma unroll
            for (int q = 0; q < 4; q++) v_[q] = Xb4[s_[q] * 8 + il];
#pragma unroll
            for (int q = 0; q < 4; q++) {
                p0 += ex2(v_[q].x); p1 += ex2(v_[q].y);
                p2 += ex2(v_[q].z); p3 += ex2(v_[q].w);
            }
        }
        for (; j < d; j++) {
            int sa = stg[s0 + j];
            uint4 va = Xb4[sa * 8 + il];
            p0 += ex2(va.x); p1 += ex2(va.y);
            p2 += ex2(va.z); p3 += ex2(va.w);
        }
        uint4 o;
        o.x = pk2(p0.x, p0.y); o.y = pk2(p1.x, p1.y);
        o.z = pk2(p2.x, p2.y); o.w = pk2(p3.x, p3.y);
        *(uint4*)&agg[nl * AP + il * 8] = o;
    }
    __syncthreads();

    // ---- stg is dead: bulk-copy prebuilt bf16 weight image into the pool ----
    for (int i = t; i < WINTS; i += 512) pool[i] = wbuf[i];
    __syncthreads();

    // ---- MFMA: 8 waves x one 16-node tile; y overlays the wave's own agg rows --
    {
        int m = lane & 15, quad = lane >> 4;
        int nl = wid * 16 + m;
        int node = b * 128 + nl;
        bhalf8 Bc0 = *(const bhalf8*)&agg[nl * AP + quad * 8];
        bhalf8 Bc1 = *(const bhalf8*)&agg[nl * AP + 32 + quad * 8];
        unsigned short* ys = &agg[nl * AP];
#pragma unroll
        for (int tile = 0; tile < 4; tile++) {
            f32x4 a;
#pragma unroll
            for (int r = 0; r < 4; r++) a[r] = b1[tile * 16 + quad * 4 + r];
            bhalf8 A0 = *(const bhalf8*)&sW1t[(tile * 16 + m) * YP + quad * 8];
            bhalf8 A1 = *(const bhalf8*)&sW1t[(tile * 16 + m) * YP + 32 + quad * 8];
            a = __builtin_amdgcn_mfma_f32_16x16x32_bf16(A0, Bc0, a, 0, 0, 0);
            a = __builtin_amdgcn_mfma_f32_16x16x32_bf16(A1, Bc1, a, 0, 0, 0);
            float y0 = a[0] > 0.f ? a[0] : 0.f, y1 = a[1] > 0.f ? a[1] : 0.f;
            float y2 = a[2] > 0.f ? a[2] : 0.f, y3 = a[3] > 0.f ? a[3] : 0.f;
            uint2 o; o.x = pk2(y0, y1); o.y = pk2(y2, y3);
            *(uint2*)&ys[tile * 16 + quad * 4] = o;
        }
        __asm__ __volatile__("s_waitcnt lgkmcnt(0)" ::: "memory");
        union { bhalf8 v; uint2 u2[2]; } Y0, Y1;
        Y0.u2[0] = *(uint2*)&ys[quad * 8];
        Y0.u2[1] = *(uint2*)&ys[quad * 8 + 4];
        Y1.u2[0] = *(uint2*)&ys[32 + quad * 8];
        Y1.u2[1] = *(uint2*)&ys[32 + quad * 8 + 4];
#pragma unroll
        for (int tile = 0; tile < 2; tile++) {
            bhalf8 A0 = *(const bhalf8*)&sW2t[(tile * 16 + m) * YP + quad * 8];
            bhalf8 A1 = *(const bhalf8*)&sW2t[(tile * 16 + m) * YP + 32 + quad * 8];
            f32x4 z = {0.f, 0.f, 0.f, 0.f};
            z = __builtin_amdgcn_mfma_f32_16x16x32_bf16(A0, Y0.v, z, 0, 0, 0);
            z = __builtin_amdgcn_mfma_f32_16x16x32_bf16(A1, Y1.v, z, 0, 0, 0);
            if (node < N_NODES) {
                uint2 o; o.x = pk2(z[0], z[1]); o.y = pk2(z[2], z[3]);
                *(uint2*)&Zb[(size_t)node * 32 + tile * 16 + quad * 4] = o;
            }
        }
    }
}

// ---------------- bucket2: sort-free, scan-free gather of Zb + b2 --------------
__global__ __launch_bounds__(512, 4) void bucket2(
    const unsigned* __restrict__ ebuf, const int* __restrict__ gcur,
    const int* __restrict__ goff,
    const uint4* __restrict__ Zb4,
    const float* __restrict__ b2, float4* __restrict__ out4) {
    __shared__ int noff[129];
    __shared__ int stg[CAP];
    int b = blockIdx.x, t = threadIdx.x;
    int base = b * CAP, cnt = gcur[b];
    int lane = t & 63, wid = t >> 6;
    if (t < 128) noff[t] = goff[b * 128 + t];
    if (t == 128) noff[128] = cnt;
    for (int i = t; i < cnt; i += 512) stg[i] = (int)ebuf[base + i];
    __syncthreads();

    // ---- gather: 4-lane group owns one node (8 ch/lane), 8 rows in flight ----
    int il = lane & 3, g = lane >> 2;
    int nl = wid * 16 + g;
    int s0 = noff[nl], d = noff[nl + 1] - s0;
    f32x2 p0 = {0.f, 0.f}, p1 = {0.f, 0.f}, p2 = {0.f, 0.f}, p3 = {0.f, 0.f};
    int j = 0;
    for (; j + 7 < d; j += 8) {  // 8 loads in flight
        int s_[8];
#pragma unroll
        for (int q = 0; q < 8; q++) s_[q] = stg[s0 + j + q];
        uint4 v_[8];
#pragma unroll
        for (int q = 0; q < 8; q++) v_[q] = Zb4[s_[q] * 4 + il];
#pragma unroll
        for (int q = 0; q < 8; q++) {
            p0 += ex2(v_[q].x); p1 += ex2(v_[q].y);
            p2 += ex2(v_[q].z); p3 += ex2(v_[q].w);
        }
    }
    for (; j + 3 < d; j += 4) {
        int s_[4];
#pragma unroll
        for (int q = 0; q < 4; q++) s_[q] = stg[s0 + j + q];
        uint4 v_[4];
#pragma unroll
        for (int q = 0; q < 4; q++) v_[q] = Zb4[s_[q] * 4 + il];
#pragma unroll
        for (int q = 0; q < 4; q++) {
            p0 += ex2(v_[q].x); p1 += ex2(v_[q].y);
            p2 += ex2(v_[q].z); p3 += ex2(v_[q].w);
        }
    }
    for (; j < d; j++) {
        int sa = stg[s0 + j];
        uint4 va = Zb4[sa * 4 + il];
        p0 += ex2(va.x); p1 += ex2(va.y);
        p2 += ex2(va.z); p3 += ex2(va.w);
    }
    int node = b * 128 + nl;
    if (node < N_NODES) {
        float4 bbA = ((const float4*)b2)[il * 2];
        float4 bbB = ((const float4*)b2)[il * 2 + 1];
        float4 oA, oB;
        oA.x = p0.x + bbA.x; oA.y = p0.y + bbA.y; oA.z = p1.x + bbA.z; oA.w = p1.y + bbA.w;
        oB.x = p2.x + bbB.x; oB.y = p2.y + bbB.y; oB.z = p3.x + bbB.z; oB.w = p3.y + bbB.w;
        out4[node * 8 + il * 2] = oA;
        out4[node * 8 + il * 2 + 1] = oB;
    }
}

extern "C" void kernel_launch(void* const* d_in, const int* in_sizes, int n_in,
                              void* d_out, int out_size, void* d_ws, size_t ws_size,
                              hipStream_t stream) {
    const float* features = (const float*)d_in[0];
    const int*   src      = (const int*)d_in[1];
    const int*   dst      = (const int*)d_in[2];
    const float* W1       = (const float*)d_in[3];
    const float* b1       = (const float*)d_in[4];
    const float* W2       = (const float*)d_in[5];
    const float* b2       = (const float*)d_in[6];

    char* p = (char*)d_ws;
    int* gcur = (int*)p;           p += 1024 * 4;
    unsigned* ebuf = (unsigned*)p; p += (size_t)NB * CAP * 4;
    uint2* Xb = (uint2*)p;         p += (size_t)N_NODES * 64 * 2;
    unsigned short* Zb = (unsigned short*)p; p += (size_t)N_NODES * 32 * 2;
    int* wbuf = (int*)p;           p += (size_t)WINTS * 4;
    int* goff = (int*)p;           p += (size_t)NB * 128 * 4;

    hipMemsetAsync(gcur, 0, NB * sizeof(int), stream);
    prep<<<NP1 + CVB, 512, 0, stream>>>((const float4*)features, Xb, src, dst, gcur,
                                        ebuf, W1, W2, wbuf);
    bucket1<<<NB, 512, 0, stream>>>(ebuf, gcur, (const uint4*)Xb, wbuf, b1, goff, Zb);
    bucket2<<<NB, 512, 0, stream>>>(ebuf, gcur, goff, (const uint4*)Zb, b2, (float4*)d_out);
}